// Round 9
// baseline (98.231 us; speedup 1.0000x reference)
//
#include <hip/hip_runtime.h>

#define NIN 784
#define WIDTH 1024
#define HALF 512
#define DEPTH 8
#define BDEPTH 10
#define BATCH 4096
#define SPLINE_DIM 20
#define NQ 18   // knot intervals [t_m, t_m+1), m = 2..19

// Clamped knot vector T[23]: [-8]*3, +-2^k/32 ladder, 0, [8]*3
__device__ float d_T[23] = {
  -8.f, -8.f, -8.f, -4.f, -2.f, -1.f, -0.5f, -0.25f, -0.125f, -0.0625f,
  -0.03125f, 0.f, 0.03125f, 0.0625f, 0.125f, 0.25f, 0.5f, 1.f, 2.f, 4.f,
  8.f, 8.f, 8.f };

// ---------------------------------------------------------------------------
// Prep kernel:
//  (a) cs[(i*10+d)*1024 + slot] = (cos th, +-sin th), sign folded by the
//      slot's partner polarity (bit9 of logical index) at step d.
//      Slot bits: [r3 r2 r1 r0 | lane5..0]; logical bit b = slot bit (b-d)%10.
//  (b) qt[(i*18+mi)*512 + w] = (A,B,C,t_m): spline activation on interval
//      m=mi+2 is exactly the quadratic A + B*u + C*u^2, u = x - t_m.
// ---------------------------------------------------------------------------
__global__ void prep_kernel(const float* __restrict__ bp,
                            const float* __restrict__ sc,
                            float2* __restrict__ cs,
                            float4* __restrict__ qt) {
  int gid = blockIdx.x * 256 + threadIdx.x;
  if (gid < DEPTH * BDEPTH * 1024) {
    int slot = gid & 1023;
    int d = (gid >> 10) % BDEPTH;
    int i = gid / (BDEPTH * 1024);
    int n = 0;
#pragma unroll
    for (int b = 0; b < 10; ++b) {
      int src = b - d; if (src < 0) src += 10;
      n |= ((slot >> src) & 1) << b;
    }
    int pj = n & 511;
    float theta = bp[(i * HALF + pj) * BDEPTH + d];
    float c = cosf(theta), s = sinf(theta);
    cs[gid] = make_float2(c, (n & 512) ? -s : s);
  }
  int gid2 = gid - DEPTH * BDEPTH * 1024;
  if (gid2 >= 0 && gid2 < (DEPTH - 1) * NQ * HALF) {
    int w = gid2 & 511;
    int mi = (gid2 >> 9) % NQ;
    int i = gid2 / (NQ * HALF);
    int m = mi + 2;
    const float* cf = sc + (i * HALF + w) * SPLINE_DIM;
    double c0 = cf[mi], c1 = cf[mi + 1], c2 = cf[mi + 2];
    double tm1 = d_T[m - 1], tm = d_T[m], tp1 = d_T[m + 1], tp2 = d_T[m + 2];
    double h = tp1 - tm;
    double us[3] = { 0.0, 0.5 * h, 0.75 * h };
    double y[3];
#pragma unroll
    for (int k = 0; k < 3; ++k) {
      double x = tm + us[k];
      double left1 = x - tm, right1 = tp1 - x, left2 = x - tm1, right2 = tp2 - x;
      double inv1 = 1.0 / (tp1 - tm);
      double N0 = right1 * inv1, N1 = left1 * inv1;
      double temp0 = N0 / (tp1 - tm1);
      double B0 = right1 * temp0;
      double saved = left2 * temp0;
      double temp1 = N1 / (tp2 - tm);
      double B1 = right2 * temp1 + saved;
      double B2 = left1 * temp1;
      y[k] = c0 * B0 + c1 * B1 + c2 * B2;
    }
    double d1 = y[1] - y[0], d2 = y[2] - y[0];
    double u1 = us[1], u2 = us[2];
    double det = u1 * u2 * (u2 - u1);
    double Bq = (d1 * u2 * u2 - d2 * u1 * u1) / det;
    double Cq = (d2 * u1 - d1 * u2) / det;
    qt[gid2] = make_float4((float)y[0], (float)Bq, (float)Cq, (float)tm);
  }
}

// ---------------------------------------------------------------------------
// Compile-time lane shuffles: DPP for xor 1/2 (VALU pipe), ds_swizzle
// immediates for 4/8/16 (no addr calc), bpermute only for 32.
// ---------------------------------------------------------------------------
template <int M>
__device__ __forceinline__ float shfx(float x) {
  if constexpr (M == 1)
    return __int_as_float(__builtin_amdgcn_mov_dpp(__float_as_int(x), 0xB1, 0xF, 0xF, true));
  else if constexpr (M == 2)
    return __int_as_float(__builtin_amdgcn_mov_dpp(__float_as_int(x), 0x4E, 0xF, 0xF, true));
  else if constexpr (M == 4)
    return __int_as_float(__builtin_amdgcn_ds_swizzle(__float_as_int(x), 0x101F));
  else if constexpr (M == 8)
    return __int_as_float(__builtin_amdgcn_ds_swizzle(__float_as_int(x), 0x201F));
  else if constexpr (M == 16)
    return __int_as_float(__builtin_amdgcn_ds_swizzle(__float_as_int(x), 0x401F));
  else
    return __shfl_xor(x, 32, 64);
}

// Quadratic spline activation: interval-find via float exponent + 1 load + 2 fma.
__device__ __forceinline__ float qspline(float x, const float4* __restrict__ qL, int w) {
  x = fminf(fmaxf(x, -8.0f), 7.9999990f);
  float ax = fabsf(x);
  unsigned bits = __float_as_uint(ax);
  int e = (int)(bits >> 23) - 127;
  int ce = e + ((bits & 0x7fffffu) ? 1 : 0);
  int m = (x > 0.f) ? (17 + e) : (5 - ce);
  m = (ax < 0.03125f) ? ((x < 0.f) ? 10 : 11) : m;
  float4 qc = qL[(m - 2) * HALF + w];
  float u = x - qc.w;
  return fmaf(u, fmaf(u, qc.z, qc.y), qc.x);
}

typedef __attribute__((address_space(3))) unsigned int lds_u32;
typedef __attribute__((address_space(1))) const unsigned int glb_u32;

// Async-stage one 5-step chunk (40 KB) of the cs table into LDS buffer `dst`
// via global_load_lds (16B/lane DMA, no VGPR round trip). 40 wave-segments of
// 1 KB; wave wv takes segments {k*8+wv}. LDS dest must be linear (wave-uniform
// base + lane*16) -- our layout already is.
__device__ __forceinline__ void stage_async(const float2* __restrict__ src,
                                            float2* dst, int wv, int lane) {
#pragma unroll
  for (int k = 0; k < 5; ++k) {
    int seg = k * 8 + wv;
    const char* g = (const char*)src + seg * 1024 + lane * 16;
    char* l = (char*)dst + seg * 1024;
    __builtin_amdgcn_global_load_lds((glb_u32*)g, (lds_u32*)l, 16, 0, 0);
  }
}

// butterfly step dd<4 from LDS buffer P slot sl: partner = reg ^ (8>>dd)
#define CSTEPL(P, sl, dd) do {                                                \
    const int _mr = 8 >> (dd);                                                \
    _Pragma("unroll") for (int r = 0; r < 16; ++r)                            \
      if ((r & _mr) == 0) {                                                   \
        float2 v = P[(sl) * 1024 + r * 64 + lane];                            \
        float a0 = s0[r], b0 = s0[r + _mr];                                   \
        s0[r]       = fmaf(a0, v.x, b0 * v.y);                                \
        s0[r + _mr] = fmaf(b0, v.x, -(a0 * v.y));                             \
      }                                                                       \
  } while (0)

// butterfly step dd>=4 from LDS buffer P slot sl: partner = lane ^ MM
#define LSTEPL(P, sl, MM) do {                                                \
    _Pragma("unroll") for (int r = 0; r < 16; ++r) {                          \
      float2 v = P[(sl) * 1024 + r * 64 + lane];                              \
      float p0 = shfx<MM>(s0[r]);                                             \
      s0[r] = fmaf(s0[r], v.x, p0 * v.y);                                     \
    }                                                                         \
  } while (0)

// ---------------------------------------------------------------------------
// Main kernel: 512-thread blocks (8 waves), one row per wave. cs table staged
// in 5-step 40 KB chunks, DOUBLE-BUFFERED and ASYNC: each phase issues the
// next chunk's global_load_lds DMA before computing the current chunk, and
// waits with a COUNTED vmcnt(5) (only the chunk issued one compute-phase ago)
// -- never vmcnt(0) in the loop. Removes the stage->drain->barrier
// serialization that R7/R8 counters implicated. 80 KB LDS -> 2 blocks/CU.
// ---------------------------------------------------------------------------
__global__ __launch_bounds__(512, 2) void fwd_kernel(
    const float* __restrict__ X, const float2* __restrict__ cs,
    const float4* __restrict__ qt, float* __restrict__ out) {
  __shared__ float2 csA[5 * 1024];   // 40 KB
  __shared__ float2 csB[5 * 1024];   // 40 KB
  int tid = threadIdx.x;
  int lane = tid & 63;
  int wv = tid >> 6;                       // 0..7
  int row = blockIdx.x * 8 + wv;

  const float* xp = X + (long)row * NIN;
  float s0[16];
#pragma unroll
  for (int r = 0; r < 16; ++r) {
    int w = r * 64 + lane;
    s0[r] = (w < NIN) ? xp[w] : 0.f;
  }

  // prologue: start DMA of layer 0 steps 0-4 into csA
  stage_async(cs, csA, wv, lane);

#pragma unroll 1
  for (int i = 0; i < DEPTH; ++i) {
    const float2* csL = cs + i * (BDEPTH * 1024);

    __syncthreads();                               // csB free (prev layer consumed)
    stage_async(csL + 5 * 1024, csB, wv, lane);    // issue steps 5-9 DMA
    asm volatile("s_waitcnt vmcnt(5)" ::: "memory"); // csA's 5 DMAs done
    __syncthreads();                               // all waves' csA DMAs landed
    CSTEPL(csA, 0, 0);
    CSTEPL(csA, 1, 1);
    CSTEPL(csA, 2, 2);
    CSTEPL(csA, 3, 3);
    LSTEPL(csA, 4, 32);

    __syncthreads();                               // csA free
    // issue next layer's steps 0-4 DMA (dummy wrap to layer 0 at i=7 keeps
    // the vmcnt count uniform; never read)
    stage_async(cs + ((i + 1) & 7) * (BDEPTH * 1024), csA, wv, lane);
    asm volatile("s_waitcnt vmcnt(5)" ::: "memory"); // csB's 5 DMAs done
    __syncthreads();                               // all waves' csB DMAs landed
    LSTEPL(csB, 0, 16);
    LSTEPL(csB, 1, 8);
    LSTEPL(csB, 2, 4);
    LSTEPL(csB, 3, 2);
    LSTEPL(csB, 4, 1);

    if (i != DEPTH - 1) {
      const float4* qL = qt + i * (NQ * HALF);
#pragma unroll
      for (int r = 8; r < 16; ++r) {
        int w = ((r - 8) << 6) | lane;
        s0[r - 8] += qspline(s0[r], qL, w);
      }
    }
  }

  float* op = out + (long)row * NIN;
#pragma unroll
  for (int r = 0; r < 13; ++r) {
    int w = r * 64 + lane;
    if (w < NIN) op[w] = s0[r];
  }
}

extern "C" void kernel_launch(void* const* d_in, const int* in_sizes, int n_in,
                              void* d_out, int out_size, void* d_ws, size_t ws_size,
                              hipStream_t stream) {
  const float* X  = (const float*)d_in[0];
  const float* bp = (const float*)d_in[1];   // [8,512,10]
  const float* sc = (const float*)d_in[2];   // [7,512,20]
  float* out = (float*)d_out;

  float2* cs = (float2*)d_ws;                                   // 655,360 B
  float4* qt = (float4*)((char*)d_ws + DEPTH * BDEPTH * 1024 * sizeof(float2)); // 1,032,192 B

  int prep_threads = DEPTH * BDEPTH * 1024 + (DEPTH - 1) * NQ * HALF; // 146,432
  prep_kernel<<<(prep_threads + 255) / 256, 256, 0, stream>>>(bp, sc, cs, qt);
  fwd_kernel<<<BATCH / 8, 512, 0, stream>>>(X, cs, qt, out);
}